// Round 6
// baseline (164.620 us; speedup 1.0000x reference)
//
#include <hip/hip_runtime.h>

typedef __attribute__((ext_vector_type(8))) _Float16 f16x8;
typedef __attribute__((ext_vector_type(4))) float f32x4;

#define CB 8
#define CC 256
#define CHW 4096

// ws layout (bytes), all 16B-aligned:
//   wAf  [9 t][8 cc][16 octile][64 lane][8] f16 @ 0        (1179648)
//   wAomF[9 t][8 cc][2 tile][64 lane][8] f16 @ 1179648    (147456)
//   descW[B*9*4096] float4       @ 1327104   (4718592)
//   descO[B*9*4096] int4         @ 6045696   (4718592)
//   xt   [B][4096 pos][256 c] f16@ 10764288  (16777216)

// Fused prep + transpose. Grid 1312 x 256:
//   bid <  288: prep (weight reformat, thread i writes one 16B fragment chunk)
//   bid >= 288: xk half-channel transpose block (b, pos-group, c-half) —
//               1024 transpose blocks (vs 512) for HBM latency hiding.
__global__ __launch_bounds__(256) void pxk(const float* __restrict__ x,
                                           const float* __restrict__ convw,
                                           const float* __restrict__ offw,
                                           const float* __restrict__ modw,
                                           _Float16* __restrict__ wAf,
                                           _Float16* __restrict__ wAomF,
                                           _Float16* __restrict__ xt) {
    __shared__ ushort tile[64][136];   // 272B row stride: 16B-aligned reads
    int bid = blockIdx.x;
    int tid = threadIdx.x;

    if (bid < 288) {
        int i = bid * 256 + tid;  // < 73728
        {
            int lane = i & 63, tl = (i >> 6) & 15, cc = (i >> 10) & 7, t = i >> 13;
            int oc = tl * 16 + (lane & 15);
            int cb = cc * 32 + (lane >> 4) * 8;
            f16x8 v;
#pragma unroll
            for (int j = 0; j < 8; ++j)
                v[j] = (_Float16)convw[oc * 2304 + (cb + j) * 9 + t];
            *(f16x8*)(wAf + (size_t)i * 8) = v;
        }
        if (i < 9216) {
            int lane = i & 63, tl = (i >> 6) & 1, cc = (i >> 7) & 7, t = i >> 10;
            int mr = tl * 16 + (lane & 15);
            int cb = cc * 32 + (lane >> 4) * 8;
            f16x8 u;
#pragma unroll
            for (int j = 0; j < 8; ++j) {
                int c = cb + j;
                float vv = 0.f;
                if (mr < 18) vv = offw[(mr * 256 + c) * 9 + t];
                else if (mr < 27) vv = modw[((mr - 18) * 256 + c) * 9 + t];
                u[j] = (_Float16)vv;
            }
            *(f16x8*)(wAomF + (size_t)i * 8) = u;
        }
        return;
    }

    int nb = bid - 288;
    int b = nb & 7, g = nb >> 3;          // XCD-pinned batch; g in 0..127
    int pos0 = (g >> 1) << 6;
    int ch0 = (g & 1) << 7;               // channel half: 0 or 128
    int p = tid & 63;
    const float* xb = x + ((size_t)b << 20);
#pragma unroll 4
    for (int rep = 0; rep < 32; rep++) {
        int c = ch0 + rep * 4 + (tid >> 6);
        _Float16 h = (_Float16)xb[((size_t)c << 12) + pos0 + p];
        tile[p][c - ch0] = __builtin_bit_cast(ushort, h);
    }
    __syncthreads();
    _Float16* xtb = xt + ((size_t)b << 20);
#pragma unroll
    for (int rep = 0; rep < 4; rep++) {
        int item = rep * 256 + tid;       // 0..1023
        int pp = item >> 4, c16 = item & 15;
        f16x8 v = *(const f16x8*)((const char*)&tile[0][0] + pp * 272 + c16 * 16);
        *(f16x8*)((char*)xtb + (((size_t)(pos0 + pp)) << 9) + (ch0 << 1) + (c16 << 4)) = v;
    }
}

// Offset/mod conv as f16 MFMA GEMM (M=32 pad, N=32 px, K=2304) + descriptor
// build. Re-gridded 1024 blocks x 128 thr (4 blocks/CU, 2 waves each): more
// independent blocks for this small latency-bound GEMM.
__global__ __launch_bounds__(128) void k1(const _Float16* __restrict__ xt,
                                          const _Float16* __restrict__ wAomF,
                                          const float* __restrict__ offb,
                                          const float* __restrict__ modb,
                                          float4* __restrict__ descW,
                                          int4* __restrict__ descO) {
    __shared__ float sEp[32][36];

    int bid = blockIdx.x;
    int b = bid & 7, yx = bid >> 3;       // XCD-pinned batch
    int y = yx >> 1, xh = yx & 1;         // y row, px half
    int tid = threadIdx.x;
    int lane = tid & 63;
    int w = __builtin_amdgcn_readfirstlane(tid >> 6);  // 0..1
    int l15 = lane & 15, oct = lane >> 4;

    const _Float16* xtb = xt + ((size_t)b << 20);
    int kylo = (y == 0) ? 1 : 0;
    int kyhi = (y == 63) ? 1 : 2;

    f32x4 acc[2];
    acc[0] = (f32x4)0.f;
    acc[1] = (f32x4)0.f;
    f16x8 Z = {};

    int pxl = (w << 4) + l15;             // 0..31 local column
    int px = (xh << 5) + pxl;             // 0..63 global column

    for (int ty = kylo; ty <= kyhi; ++ty) {
        int yy = y + ty - 1;
#pragma unroll
        for (int tx = 0; tx < 3; ++tx) {
            int t = ty * 3 + tx;
            int xx = px + tx - 1;
            bool val = (xx >= 0 && xx < 64);
            int xxc = min(max(xx, 0), 63);
            const f16x8* bp = (const f16x8*)(xtb + (((yy << 6) + xxc) << 8) + oct * 8);
            const f16x8* wf = (const f16x8*)wAomF + (size_t)t * 16 * 64 + lane;
#pragma unroll
            for (int c0 = 0; c0 < 256; c0 += 32) {
                f16x8 bf = bp[c0 >> 3];
                if (!val) bf = Z;
                int cc = c0 >> 5;
#pragma unroll
                for (int m = 0; m < 2; m++) {
                    f16x8 af = wf[(cc * 2 + m) * 64];
                    acc[m] = __builtin_amdgcn_mfma_f32_16x16x32_f16(af, bf, acc[m], 0, 0, 0);
                }
            }
        }
    }

#pragma unroll
    for (int m = 0; m < 2; m++) {
#pragma unroll
        for (int r = 0; r < 4; r++) {
            int row = (m << 4) + (oct << 2) + r;
            if (row < 27) sEp[row][pxl] = acc[m][r];
        }
    }
    __syncthreads();

    int gq = tid >> 5;                     // 0..3
    int xl = tid & 31;
    if (gq < 3) {
        int xx2 = (xh << 5) + xl;
        float lx = -1.0f + xx2 * (2.0f / 63.0f);
        float ly = -1.0f + y * (2.0f / 63.0f);
#pragma unroll
        for (int j = 0; j < 3; j++) {
            int k = gq * 3 + j;
            float gx = sEp[k][xl] + offb[k] + lx;
            gx = fminf(fmaxf(gx, -1.f), 1.f);
            float gy = sEp[9 + k][xl] + offb[9 + k] + ly;
            gy = fminf(fmaxf(gy, -1.f), 1.f);
            float m = sEp[18 + k][xl] + modb[k];
            float ix = (gx + 1.0f) * 0.5f * 63.0f;
            float iy = (gy + 1.0f) * 0.5f * 63.0f;
            float fx = floorf(ix), fy = floorf(iy);
            float wx = ix - fx, wy = iy - fy;
            int x0 = min(max((int)fx, 0), 63);
            int x1 = min(x0 + 1, 63);
            int y0 = min(max((int)fy, 0), 63);
            int y1 = min(y0 + 1, 63);
            float w00 = (1.f - wx) * (1.f - wy) * m;
            float w01 = wx * (1.f - wy) * m;
            float w10 = (1.f - wx) * wy * m;
            float w11 = wx * wy * m;
            int di = ((b * 9 + k) << 12) + (y << 6) + xx2;
            descW[di] = make_float4(w00, w01, w10, w11);
            descO[di] = make_int4(((y0 << 6) + x0) << 9, ((y0 << 6) + x1) << 9,
                                  ((y1 << 6) + x0) << 9, ((y1 << 6) + x1) << 9);
        }
    }
}

// Fused gather + f16 MFMA implicit GEMM — R4 body (proven 63.5 µs) with the
// phase loop pinned to unroll-2 (tight I-cache footprint; the 18-way unrolled
// body was ~25-30KB, at the 32KB L1I boundary).
struct SmK2 {
    char cmb[2][2][8192];   // [dbuf][sub]; chunk16 at (ox*8+(cs^(ox&7)))*16
    float4 dW[2][64];
    int4 dO[2][64];
};
__global__ __launch_bounds__(512, 4) void k2(const _Float16* __restrict__ xt,
                                             const _Float16* __restrict__ wAf,
                                             const float4* __restrict__ descW,
                                             const int4* __restrict__ descO,
                                             const float* __restrict__ convb,
                                             float* __restrict__ out) {
    __shared__ union SU {
        SmK2 m;
        f32x4 sred[2048];   // aliases cmb (32KB) for the cross-ks epilogue
    } S;

    int bid = blockIdx.x;
    int b = bid & 7, oy = bid >> 3;  // XCD-bijective: batch -> XCD
    int tid = threadIdx.x;
    int l = tid & 63;
    int wid = __builtin_amdgcn_readfirstlane(tid >> 6);
    int mgrp = wid & 3, ks = wid >> 2;
    int oct = l >> 4, l15 = l & 15;

    const char* xtb = (const char*)(xt + ((size_t)b << 20));

    f32x4 acc[4][4];
#pragma unroll
    for (int mt = 0; mt < 4; mt++)
#pragma unroll
        for (int nt = 0; nt < 4; nt++) acc[mt][nt] = (f32x4)0.f;

    // producer constants: thread -> (ox, 16B chunk)
    int p_ox = (tid >> 3) & 63;
    int p_cs = tid & 7;
    int csl = (p_ox << 7) + ((p_cs ^ (p_ox & 7)) << 4);
    const char* xtb_cs = xtb + p_cs * 16;

    // consumer constant: B-fragment byte offset within an 8KB sub-buffer
    int boff = (l15 << 7) + ((((ks << 2) + oct) ^ (l15 & 7)) << 4);

    auto stage_desc = [&](int t) {   // tid < 64 only
        int slot = t & 1;
        int xx = tid;
        int ky = t / 3, kx = t % 3;
        int yy = oy + ky - 1;
        int xp = xx + kx - 1;
        float4 w4s = make_float4(0.f, 0.f, 0.f, 0.f);
        int4 o4 = make_int4(0, 0, 0, 0);
        if (yy >= 0 && yy < 64 && xp >= 0 && xp < 64) {
            int di = ((b * 9 + t) << 12) + (yy << 6) + xp;
            w4s = descW[di];
            o4 = descO[di];
        }
        S.m.dW[slot][xx] = w4s;
        S.m.dO[slot][xx] = o4;
    };

    // per-tap register-cached descriptor for the tap currently being ISSUED
    int rdo0, rdo1, rdo2, rdo3;
    _Float16 rh0, rh1, rh2, rh3;
    auto refresh_desc = [&](int t) {
        int slot = t & 1;
        int4 o4 = S.m.dO[slot][p_ox];
        rdo0 = o4.x; rdo1 = o4.y; rdo2 = o4.z; rdo3 = o4.w;
        float4 w4 = S.m.dW[slot][p_ox];
        rh0 = (_Float16)w4.x; rh1 = (_Float16)w4.y;
        rh2 = (_Float16)w4.z; rh3 = (_Float16)w4.w;
    };

    auto issue_q = [&](f16x8* cr, int q) {
        const char* base = xtb_cs + (q << 7);
        cr[0] = *(const f16x8*)(base + rdo0);
        cr[1] = *(const f16x8*)(base + rdo1);
        cr[2] = *(const f16x8*)(base + rdo2);
        cr[3] = *(const f16x8*)(base + rdo3);
    };

    auto comb_write = [&](const f16x8* cr, char* dst) {
        f16x8 W0 = {rh0, rh0, rh0, rh0, rh0, rh0, rh0, rh0};
        f16x8 W1 = {rh1, rh1, rh1, rh1, rh1, rh1, rh1, rh1};
        f16x8 W2 = {rh2, rh2, rh2, rh2, rh2, rh2, rh2, rh2};
        f16x8 W3 = {rh3, rh3, rh3, rh3, rh3, rh3, rh3, rh3};
        f16x8 r = cr[0] * W0 + cr[1] * W1 + cr[2] * W2 + cr[3] * W3;
        *(f16x8*)(dst + csl) = r;
    };

    auto load_afr = [&](f16x8* afr, int m) {   // quarter index m = t*4+q
        int t = m >> 2, q = m & 3;
        const f16x8* wf = (const f16x8*)wAf +
                          ((size_t)((t * 8 + q * 2 + ks) * 16 + mgrp * 4)) * 64 + l;
        afr[0] = wf[0];
        afr[1] = wf[64];
        afr[2] = wf[128];
        afr[3] = wf[192];
    };

    auto do_mfma = [&](const char* src, const f16x8* afr) {
        f16x8 bfr[4];
#pragma unroll
        for (int nt = 0; nt < 4; ++nt)
            bfr[nt] = *(const f16x8*)(src + boff + (nt << 11));
#pragma unroll
        for (int nt = 0; nt < 4; ++nt)
#pragma unroll
            for (int mt = 0; mt < 4; ++mt)
                acc[mt][nt] = __builtin_amdgcn_mfma_f32_16x16x32_f16(
                    afr[mt], bfr[nt], acc[mt][nt], 0, 0, 0);
    };

    // ---- prologue: desc tap 0; quarters 0,1 into cmb[0]
    if (tid < 64) stage_desc(0);
    __syncthreads();
    refresh_desc(0);
    {
        f16x8 c0[4];
        issue_q(c0, 0);
        comb_write(c0, S.m.cmb[0][0]);
        issue_q(c0, 1);
        comb_write(c0, S.m.cmb[0][1]);
    }
    __syncthreads();

    // ---- 18 double-length phases, one barrier each (unroll 2: tight loop)
#pragma unroll 2
    for (int P = 0; P < 18; ++P) {
        int pb = P & 1;
        int t = P >> 1;
        bool more = (P < 17);

        if (!(P & 1)) {
            if (t + 1 <= 8 && tid < 64) stage_desc(t + 1);
        } else if (more) {
            refresh_desc((P + 1) >> 1);   // tap for the quarters issued this phase
        }

        f16x8 afr[4];
        f16x8 cr[4];

        // --- sub0 ---
        load_afr(afr, 2 * P);
        if (more) issue_q(cr, (2 * P + 2) & 3);
        do_mfma(S.m.cmb[pb][0], afr);
        load_afr(afr, 2 * P + 1);             // reuse afr regs for sub1
        if (more) comb_write(cr, S.m.cmb[pb ^ 1][0]);

        // --- sub1 ---
        if (more) issue_q(cr, (2 * P + 3) & 3);   // reuse cr regs
        do_mfma(S.m.cmb[pb][1], afr);
        if (more) comb_write(cr, S.m.cmb[pb ^ 1][1]);

        __syncthreads();
    }

    // ---- cross-ks reduce: ks=1 partials added into ks=0 accumulators
#pragma unroll
    for (int R = 0; R < 2; ++R) {
        if (ks == 1) {
#pragma unroll
            for (int mtl = 0; mtl < 2; ++mtl) {
#pragma unroll
                for (int nt = 0; nt < 4; ++nt) {
                    int fi = (((mgrp << 1) + mtl) << 8) + (((nt << 4) + l15) << 2) + oct;
                    S.sred[fi] = acc[(R << 1) + mtl][nt];
                }
            }
        }
        __syncthreads();
        if (ks == 0) {
#pragma unroll
            for (int mtl = 0; mtl < 2; ++mtl) {
#pragma unroll
                for (int nt = 0; nt < 4; ++nt) {
                    int fi = (((mgrp << 1) + mtl) << 8) + (((nt << 4) + l15) << 2) + oct;
                    acc[(R << 1) + mtl][nt] += S.sred[fi];
                }
            }
        }
        __syncthreads();
    }

    if (ks == 0) {
        size_t outb = ((size_t)b << 20);
#pragma unroll
        for (int mt = 0; mt < 4; ++mt) {
#pragma unroll
            for (int nt = 0; nt < 4; ++nt) {
                int ox = (nt << 4) + l15;
#pragma unroll
                for (int r = 0; r < 4; ++r) {
                    int oc = (mgrp << 6) + (mt << 4) + (oct << 2) + r;
                    out[outb + (size_t)oc * 4096 + (oy << 6) + ox] = acc[mt][nt][r] + convb[oc];
                }
            }
        }
    }
}

extern "C" void kernel_launch(void* const* d_in, const int* in_sizes, int n_in,
                              void* d_out, int out_size, void* d_ws, size_t ws_size,
                              hipStream_t stream) {
    const float* x     = (const float*)d_in[0];
    const float* convw = (const float*)d_in[1];
    const float* convb = (const float*)d_in[2];
    const float* offw  = (const float*)d_in[3];
    const float* offb  = (const float*)d_in[4];
    const float* modw  = (const float*)d_in[5];
    const float* modb  = (const float*)d_in[6];
    float* out = (float*)d_out;

    char* ws = (char*)d_ws;
    _Float16* wAf   = (_Float16*)(ws);
    _Float16* wAomF = (_Float16*)(ws + 1179648);
    float4*   descW = (float4*)(ws + 1327104);
    int4*     descO = (int4*)(ws + 6045696);
    _Float16* xt    = (_Float16*)(ws + 10764288);

    hipLaunchKernelGGL(pxk, dim3(1312), dim3(256), 0, stream, x, convw, offw, modw, wAf, wAomF, xt);
    hipLaunchKernelGGL(k1, dim3(1024), dim3(128), 0, stream, xt, wAomF, offb, modb, descW, descO);
    hipLaunchKernelGGL(k2, dim3(512), dim3(512), 0, stream, xt, wAf, descW, descO, convb, out);
}

// Round 7
// 98.881 us; speedup vs baseline: 1.6648x; 1.6648x over previous
//
#include <hip/hip_runtime.h>

typedef __attribute__((ext_vector_type(8))) _Float16 f16x8;
typedef __attribute__((ext_vector_type(4))) float f32x4;

#define CB 8
#define CC 256
#define CHW 4096

// ws layout (bytes), all 16B-aligned:
//   wAf  [9 t][8 cc][16 octile][64 lane][8] f16 @ 0        (1179648)
//   wAomF[9 t][8 cc][2 tile][64 lane][8] f16 @ 1179648    (147456)
//   descW[B*9*4096] float4       @ 1327104   (4718592)
//   descO[B*9*4096] int4         @ 6045696   (4718592)
//   xt   [B][4096 pos][256 c] f16@ 10764288  (16777216)

// Fused prep + transpose (R6, measured good). Grid 1312 x 256:
//   bid <  288: prep (weight reformat, thread i writes one 16B fragment chunk)
//   bid >= 288: half-channel transpose block (b, pos-group, c-half).
__global__ __launch_bounds__(256) void pxk(const float* __restrict__ x,
                                           const float* __restrict__ convw,
                                           const float* __restrict__ offw,
                                           const float* __restrict__ modw,
                                           _Float16* __restrict__ wAf,
                                           _Float16* __restrict__ wAomF,
                                           _Float16* __restrict__ xt) {
    __shared__ ushort tile[64][136];   // 272B row stride: 16B-aligned reads
    int bid = blockIdx.x;
    int tid = threadIdx.x;

    if (bid < 288) {
        int i = bid * 256 + tid;  // < 73728
        {
            int lane = i & 63, tl = (i >> 6) & 15, cc = (i >> 10) & 7, t = i >> 13;
            int oc = tl * 16 + (lane & 15);
            int cb = cc * 32 + (lane >> 4) * 8;
            f16x8 v;
#pragma unroll
            for (int j = 0; j < 8; ++j)
                v[j] = (_Float16)convw[oc * 2304 + (cb + j) * 9 + t];
            *(f16x8*)(wAf + (size_t)i * 8) = v;
        }
        if (i < 9216) {
            int lane = i & 63, tl = (i >> 6) & 1, cc = (i >> 7) & 7, t = i >> 10;
            int mr = tl * 16 + (lane & 15);
            int cb = cc * 32 + (lane >> 4) * 8;
            f16x8 u;
#pragma unroll
            for (int j = 0; j < 8; ++j) {
                int c = cb + j;
                float vv = 0.f;
                if (mr < 18) vv = offw[(mr * 256 + c) * 9 + t];
                else if (mr < 27) vv = modw[((mr - 18) * 256 + c) * 9 + t];
                u[j] = (_Float16)vv;
            }
            *(f16x8*)(wAomF + (size_t)i * 8) = u;
        }
        return;
    }

    int nb = bid - 288;
    int b = nb & 7, g = nb >> 3;          // XCD-pinned batch; g in 0..127
    int pos0 = (g >> 1) << 6;
    int ch0 = (g & 1) << 7;               // channel half: 0 or 128
    int p = tid & 63;
    const float* xb = x + ((size_t)b << 20);
#pragma unroll 4
    for (int rep = 0; rep < 32; rep++) {
        int c = ch0 + rep * 4 + (tid >> 6);
        _Float16 h = (_Float16)xb[((size_t)c << 12) + pos0 + p];
        tile[p][c - ch0] = __builtin_bit_cast(ushort, h);
    }
    __syncthreads();
    _Float16* xtb = xt + ((size_t)b << 20);
#pragma unroll
    for (int rep = 0; rep < 4; rep++) {
        int item = rep * 256 + tid;       // 0..1023
        int pp = item >> 4, c16 = item & 15;
        f16x8 v = *(const f16x8*)((const char*)&tile[0][0] + pp * 272 + c16 * 16);
        *(f16x8*)((char*)xtb + (((size_t)(pos0 + pp)) << 9) + (ch0 << 1) + (c16 << 4)) = v;
    }
}

// Offset/mod conv as f16 MFMA GEMM (M=32 pad, N=32 px, K=2304) + descriptor
// build (R6, measured good). 1024 blocks x 128 thr (4 blocks/CU, 2 waves).
__global__ __launch_bounds__(128) void k1(const _Float16* __restrict__ xt,
                                          const _Float16* __restrict__ wAomF,
                                          const float* __restrict__ offb,
                                          const float* __restrict__ modb,
                                          float4* __restrict__ descW,
                                          int4* __restrict__ descO) {
    __shared__ float sEp[32][36];

    int bid = blockIdx.x;
    int b = bid & 7, yx = bid >> 3;       // XCD-pinned batch
    int y = yx >> 1, xh = yx & 1;         // y row, px half
    int tid = threadIdx.x;
    int lane = tid & 63;
    int w = __builtin_amdgcn_readfirstlane(tid >> 6);  // 0..1
    int l15 = lane & 15, oct = lane >> 4;

    const _Float16* xtb = xt + ((size_t)b << 20);
    int kylo = (y == 0) ? 1 : 0;
    int kyhi = (y == 63) ? 1 : 2;

    f32x4 acc[2];
    acc[0] = (f32x4)0.f;
    acc[1] = (f32x4)0.f;
    f16x8 Z = {};

    int pxl = (w << 4) + l15;             // 0..31 local column
    int px = (xh << 5) + pxl;             // 0..63 global column

    for (int ty = kylo; ty <= kyhi; ++ty) {
        int yy = y + ty - 1;
#pragma unroll
        for (int tx = 0; tx < 3; ++tx) {
            int t = ty * 3 + tx;
            int xx = px + tx - 1;
            bool val = (xx >= 0 && xx < 64);
            int xxc = min(max(xx, 0), 63);
            const f16x8* bp = (const f16x8*)(xtb + (((yy << 6) + xxc) << 8) + oct * 8);
            const f16x8* wf = (const f16x8*)wAomF + (size_t)t * 16 * 64 + lane;
#pragma unroll
            for (int c0 = 0; c0 < 256; c0 += 32) {
                f16x8 bf = bp[c0 >> 3];
                if (!val) bf = Z;
                int cc = c0 >> 5;
#pragma unroll
                for (int m = 0; m < 2; m++) {
                    f16x8 af = wf[(cc * 2 + m) * 64];
                    acc[m] = __builtin_amdgcn_mfma_f32_16x16x32_f16(af, bf, acc[m], 0, 0, 0);
                }
            }
        }
    }

#pragma unroll
    for (int m = 0; m < 2; m++) {
#pragma unroll
        for (int r = 0; r < 4; r++) {
            int row = (m << 4) + (oct << 2) + r;
            if (row < 27) sEp[row][pxl] = acc[m][r];
        }
    }
    __syncthreads();

    int gq = tid >> 5;                     // 0..3
    int xl = tid & 31;
    if (gq < 3) {
        int xx2 = (xh << 5) + xl;
        float lx = -1.0f + xx2 * (2.0f / 63.0f);
        float ly = -1.0f + y * (2.0f / 63.0f);
#pragma unroll
        for (int j = 0; j < 3; j++) {
            int k = gq * 3 + j;
            float gx = sEp[k][xl] + offb[k] + lx;
            gx = fminf(fmaxf(gx, -1.f), 1.f);
            float gy = sEp[9 + k][xl] + offb[9 + k] + ly;
            gy = fminf(fmaxf(gy, -1.f), 1.f);
            float m = sEp[18 + k][xl] + modb[k];
            float ix = (gx + 1.0f) * 0.5f * 63.0f;
            float iy = (gy + 1.0f) * 0.5f * 63.0f;
            float fx = floorf(ix), fy = floorf(iy);
            float wx = ix - fx, wy = iy - fy;
            int x0 = min(max((int)fx, 0), 63);
            int x1 = min(x0 + 1, 63);
            int y0 = min(max((int)fy, 0), 63);
            int y1 = min(y0 + 1, 63);
            float w00 = (1.f - wx) * (1.f - wy) * m;
            float w01 = wx * (1.f - wy) * m;
            float w10 = (1.f - wx) * wy * m;
            float w11 = wx * wy * m;
            int di = ((b * 9 + k) << 12) + (y << 6) + xx2;
            descW[di] = make_float4(w00, w01, w10, w11);
            descO[di] = make_int4(((y0 << 6) + x0) << 9, ((y0 << 6) + x1) << 9,
                                  ((y1 << 6) + x0) << 9, ((y1 << 6) + x1) << 9);
        }
    }
}

// Fused gather + f16 MFMA implicit GEMM — R1 body verbatim (measured
// 62.3-62.8 µs, VGPR 52, no spill). 1-row blocks, 2 blocks/CU.
// Block (b, oy): out 256 oc x 64 px. 512 thr = 8 waves; wave = 32 oc x 64 px.
// 36 quarter-phases, fully unrolled (partial unroll spills — R6 lesson).
__global__ __launch_bounds__(512, 4) void k2(const _Float16* __restrict__ xt,
                                             const _Float16* __restrict__ wAf,
                                             const float4* __restrict__ descW,
                                             const int4* __restrict__ descO,
                                             const float* __restrict__ convb,
                                             float* __restrict__ out) {
    __shared__ char cmb[2][8192];    // chunk16(ox,cs) at (ox*8 + (cs^(ox&7)))*16
    __shared__ float4 sDW[2][64];
    __shared__ int sDO[2][256];      // [tap&1][ox*4+corner] byte offsets into xtb

    int bid = blockIdx.x;
    int b = bid & 7, oy = bid >> 3;  // XCD-bijective: batch -> XCD
    int tid = threadIdx.x;
    int l = tid & 63;
    int wid = __builtin_amdgcn_readfirstlane(tid >> 6);
    int oct = l >> 4, l15 = l & 15;

    const char* xtb = (const char*)(xt + ((size_t)b << 20));

    f32x4 acc[2][4];
#pragma unroll
    for (int mt = 0; mt < 2; mt++)
#pragma unroll
        for (int nt = 0; nt < 4; nt++) acc[mt][nt] = (f32x4)0.f;

    // producer constants: thread -> (ox, 16B chunk)
    int p_ox = (tid >> 3) & 63;
    int p_cs = tid & 7;
    int csl = (p_ox << 7) + ((p_cs ^ (p_ox & 7)) << 4);

    auto stage_desc = [&](int t) {   // tid < 64 only
        int slot = t & 1;
        int xx = tid;
        int ky = t / 3, kx = t % 3;
        int yy = oy + ky - 1;
        int xp = xx + kx - 1;
        float4 w4s = make_float4(0.f, 0.f, 0.f, 0.f);
        int4 o4 = make_int4(0, 0, 0, 0);
        if (yy >= 0 && yy < 64 && xp >= 0 && xp < 64) {
            int di = ((b * 9 + t) << 12) + (yy << 6) + xp;
            w4s = descW[di];
            o4 = descO[di];
        }
        sDW[slot][xx] = w4s;
        sDO[slot][xx * 4 + 0] = o4.x;
        sDO[slot][xx * 4 + 1] = o4.y;
        sDO[slot][xx * 4 + 2] = o4.z;
        sDO[slot][xx * 4 + 3] = o4.w;
    };

    f16x8 cr[4];
    float4 w4;

    auto load_corners = [&](int t, int q) {
        int slot = t & 1;
        const int* dof = &sDO[slot][p_ox * 4];
        w4 = sDW[slot][p_ox];
#pragma unroll
        for (int c = 0; c < 4; ++c)
            cr[c] = *(const f16x8*)(xtb + dof[c] + q * 128 + p_cs * 16);
    };

    auto write_cmb = [&](int nb) {
        _Float16 h0 = (_Float16)w4.x, h1 = (_Float16)w4.y;
        _Float16 h2 = (_Float16)w4.z, h3 = (_Float16)w4.w;
        f16x8 W0 = {h0, h0, h0, h0, h0, h0, h0, h0};
        f16x8 W1 = {h1, h1, h1, h1, h1, h1, h1, h1};
        f16x8 W2 = {h2, h2, h2, h2, h2, h2, h2, h2};
        f16x8 W3 = {h3, h3, h3, h3, h3, h3, h3, h3};
        f16x8 r = cr[0] * W0 + cr[1] * W1 + cr[2] * W2 + cr[3] * W3;
        *(f16x8*)(cmb[nb] + csl) = r;
    };

    if (tid < 64) stage_desc(0);
    __syncthreads();
    load_corners(0, 0);
    write_cmb(0);
    __syncthreads();

    for (int p = 0; p < 36; ++p) {
        int t = p >> 2, q = p & 3, pb = p & 1;
        bool hasNext = (p + 1 < 36);

        // --- A-fragments for this quarter: 4 x 1KB coalesced, unique per wave ---
        f16x8 afr[2][2];
        {
            const f16x8* wf = (const f16x8*)wAf +
                              ((size_t)((t * 8 + q * 2) * 16) + wid * 2) * 64 + l;
            afr[0][0] = wf[0];
            afr[0][1] = wf[64];
            afr[1][0] = wf[16 * 64];
            afr[1][1] = wf[17 * 64];
        }

        // --- corner loads for quarter p+1 (land under the MFMAs) ---
        if (hasNext) load_corners((p + 1) >> 2, (p + 1) & 3);
        if (q == 0 && t + 1 < 9 && tid < 64) stage_desc(t + 1);

        // --- 16 MFMA on cmb[pb] ---
        const char* src = cmb[pb];
        __builtin_amdgcn_s_setprio(1);
#pragma unroll
        for (int ks2 = 0; ks2 < 2; ++ks2) {
            f16x8 bfr[4];
            int cs = (ks2 << 2) + oct;
#pragma unroll
            for (int nt = 0; nt < 4; ++nt) {
                int ox = (nt << 4) + l15;
                bfr[nt] = *(const f16x8*)(src + (ox << 7) + ((cs ^ (ox & 7)) << 4));
            }
#pragma unroll
            for (int mt = 0; mt < 2; ++mt)
#pragma unroll
                for (int nt = 0; nt < 4; ++nt)
                    acc[mt][nt] = __builtin_amdgcn_mfma_f32_16x16x32_f16(
                        afr[ks2][mt], bfr[nt], acc[mt][nt], 0, 0, 0);
        }
        __builtin_amdgcn_s_setprio(0);

        // --- combine quarter p+1 in regs, write the other buffer ---
        if (hasNext) write_cmb(pb ^ 1);
        __syncthreads();
    }

    size_t outb = ((size_t)b << 20);
#pragma unroll
    for (int mt = 0; mt < 2; ++mt) {
#pragma unroll
        for (int nt = 0; nt < 4; ++nt) {
            int ox = (nt << 4) + l15;
#pragma unroll
            for (int r = 0; r < 4; ++r) {
                int oc = (wid << 5) + (mt << 4) + (oct << 2) + r;
                out[outb + (size_t)oc * 4096 + (oy << 6) + ox] = acc[mt][nt][r] + convb[oc];
            }
        }
    }
}

extern "C" void kernel_launch(void* const* d_in, const int* in_sizes, int n_in,
                              void* d_out, int out_size, void* d_ws, size_t ws_size,
                              hipStream_t stream) {
    const float* x     = (const float*)d_in[0];
    const float* convw = (const float*)d_in[1];
    const float* convb = (const float*)d_in[2];
    const float* offw  = (const float*)d_in[3];
    const float* offb  = (const float*)d_in[4];
    const float* modw  = (const float*)d_in[5];
    const float* modb  = (const float*)d_in[6];
    float* out = (float*)d_out;

    char* ws = (char*)d_ws;
    _Float16* wAf   = (_Float16*)(ws);
    _Float16* wAomF = (_Float16*)(ws + 1179648);
    float4*   descW = (float4*)(ws + 1327104);
    int4*     descO = (int4*)(ws + 6045696);
    _Float16* xt    = (_Float16*)(ws + 10764288);

    hipLaunchKernelGGL(pxk, dim3(1312), dim3(256), 0, stream, x, convw, offw, modw, wAf, wAomF, xt);
    hipLaunchKernelGGL(k1, dim3(1024), dim3(128), 0, stream, xt, wAomF, offb, modb, descW, descO);
    hipLaunchKernelGGL(k2, dim3(512), dim3(512), 0, stream, xt, wAf, descW, descO, convb, out);
}